// Round 1
// baseline (207.332 us; speedup 1.0000x reference)
//
#include <hip/hip_runtime.h>
#include <stdint.h>

// R11: gemm_k rebuilt on the m201 8-wave schedule (T3+T4+T5): 256x256 tile, BK=128 i8,
// 512 thr / 8 waves (2m x 4n, 128x64 per wave), double-buffered 128KB LDS, counted
// s_waitcnt vmcnt(8) (never 0 in main loop) + raw s_barrier, setprio around MFMA clusters.
// Old loop drained vmcnt(0) at every __syncthreads -> staging fully exposed (MfmaUtil 29%).
// Numerics bit-identical to R10 (same i8 MFMA accumulation order, same epilogue math).
// prep_k / resolve_k / finalize_k unchanged from R10.

#define B_DIM 8192
#define D_DIM 1024
#define N_DIM 4096
#define ND ((size_t)N_DIM * D_DIM)
#define LRc 0.02f
#define ATc 0.3f
#define EMAc (0.02f * 0.1f)   // LR*DSBETA = 0.002
#define QS 32.0f              // i8 quant scale
#define INV_QS2 (1.0f / (QS * QS))
#define MARGIN_G 10.0f        // candidate window in g-units (~9 sigma of i8 error; +0.5 nib slack in test)

typedef int intv4 __attribute__((ext_vector_type(4)));

__device__ __forceinline__ void async16(void* lds, const void* g) {
    __builtin_amdgcn_global_load_lds((const __attribute__((address_space(1))) void*)g,
                                     (__attribute__((address_space(3))) void*)lds, 16, 0, 0);
}

__device__ __forceinline__ int q8(float v) {
    return (int)rintf(fminf(fmaxf(v * QS, -127.0f), 127.0f));
}

__device__ __forceinline__ unsigned pack4(float4 v) {
    return (unsigned)(q8(v.x) & 255) | ((unsigned)(q8(v.y) & 255) << 8)
         | ((unsigned)(q8(v.z) & 255) << 16) | ((unsigned)(q8(v.w) & 255) << 24);
}

// ---------------- prep: quantize x/w to i8, norms, gb. One wave per row. ----------------
__global__ __launch_bounds__(256) void prep_k(const float* __restrict__ x, const float* __restrict__ w,
                                              const float* __restrict__ rel,
                                              signed char* __restrict__ xq, signed char* __restrict__ wq,
                                              float* __restrict__ x2p, float* __restrict__ w2p,
                                              float* __restrict__ rsump, float* __restrict__ gbp) {
    const int lane = threadIdx.x & 63, wave = threadIdx.x >> 6;
    const int row = (blockIdx.x << 2) + wave;
    if (row < B_DIM) {
        const float4* xr = (const float4*)(x + (size_t)row * D_DIM);
        unsigned* xqr = (unsigned*)(xq + (size_t)row * D_DIM);
        float ss = 0.f;
#pragma unroll
        for (int j = 0; j < 4; ++j) {
            const float4 v = xr[lane + j * 64];
            ss += v.x * v.x + v.y * v.y + v.z * v.z + v.w * v.w;
            xqr[lane + j * 64] = pack4(v);
        }
#pragma unroll
        for (int o = 32; o; o >>= 1) ss += __shfl_xor(ss, o);
        if (lane == 0) x2p[row] = ss;
    } else {
        const int n = row - B_DIM;
        const float4* wr = (const float4*)(w + (size_t)n * D_DIM);
        const float4* rr = (const float4*)(rel + (size_t)n * D_DIM);
        unsigned* wqr = (unsigned*)(wq + (size_t)n * D_DIM);
        float ss = 0.f, rs = 0.f;
#pragma unroll
        for (int j = 0; j < 4; ++j) {
            const float4 v = wr[lane + j * 64];
            const float4 rv = rr[lane + j * 64];
            ss += v.x * v.x + v.y * v.y + v.z * v.z + v.w * v.w;
            rs += rv.x + rv.y + rv.z + rv.w;
            wqr[lane + j * 64] = pack4(v);
        }
#pragma unroll
        for (int o = 32; o; o >>= 1) { ss += __shfl_xor(ss, o); rs += __shfl_xor(rs, o); }
        if (lane == 0) {
            w2p[n] = ss;
            rsump[n] = rs;
            // act = nc*D/(D + x2 + g), g = w2 - 2s + D*1e-7/rs -> rank by min g
            gbp[n] = ss + (1e-7f * (float)D_DIM) / rs;
        }
    }
}

// ---------------- i8 GEMM -> per-64col tile min (f32) + 4-bit residuals ----------------
// 256x256 block tile, BK=128, 8 waves (2m x 4n), each wave owns 128x64 (8x4 of 16x16x64 MFMA).
// Double-buffered LDS (2 x 64KB), ring-2 prefetch distance 1, counted vmcnt(8).
__global__ __launch_bounds__(512, 2) void gemm_k(const signed char* __restrict__ xq,
                                                 const signed char* __restrict__ wq,
                                                 const float* __restrict__ gbp,
                                                 unsigned short* __restrict__ resq,
                                                 float* __restrict__ tminp) {
    extern __shared__ char smem[];   // 2 slots x (A 32KB + B 32KB) = 128KB
    const int t = threadIdx.x;
    const int mt = blockIdx.x & 31;   // 32 m-tiles (B/256)
    const int nt = blockIdx.x >> 5;   // 16 n-tiles (N/256)
    const int m0 = mt * 256, n0 = nt * 256;
    const int lane = t & 63, wave = t >> 6;
    const int q = lane >> 4, ln = lane & 15;
    const int wm = wave >> 2, wn = wave & 3;   // 2 x 4 wave grid

    intv4 acc[8][4];
#pragma unroll
    for (int i = 0; i < 8; ++i)
#pragma unroll
        for (int j = 0; j < 4; ++j) acc[i][j] = (intv4){0, 0, 0, 0};

    // staging swizzle (same as R10): slot L holds (row r=L>>3, chunk c=(L&7)^(r&7));
    // read of (row r, chunk k) is at slot r*8 + (k^(r&7)). Bank-conflict-free (measured 0).
    int gOff[4], lOff[4];
#pragma unroll
    for (int s = 0; s < 4; ++s) {
        const int L = t + s * 512;
        const int r = L >> 3;
        gOff[s] = r * D_DIM + ((L & 7) ^ (r & 7)) * 16;
        lOff[s] = L * 16;
    }
    const signed char* Ap = xq + (size_t)m0 * D_DIM;
    const signed char* Bp = wq + (size_t)n0 * D_DIM;

    // per-thread ds_read bases: row&7 == ln&7 (i*16, wm*128, wn*64, j*16 are all %8==0)
    const int baseA = (wm * 128 + ln) * 128;
    const int baseB = (wn * 64 + ln) * 128;

#define STAGE_KT(kt, slot) do {                                                     \
        char* sa_ = smem + (slot) * 65536;                                          \
        const int k0_ = (kt) * 128;                                                 \
        _Pragma("unroll")                                                           \
        for (int s_ = 0; s_ < 4; ++s_) async16(sa_ + lOff[s_], Ap + gOff[s_] + k0_);\
        _Pragma("unroll")                                                           \
        for (int s_ = 0; s_ < 4; ++s_) async16(sa_ + 32768 + lOff[s_], Bp + gOff[s_] + k0_); \
    } while (0)

#define COMPUTE_KT(slot) do {                                                       \
        const char* sa_ = smem + (slot) * 65536;                                    \
        const char* sb_ = sa_ + 32768;                                              \
        _Pragma("unroll")                                                           \
        for (int ks = 0; ks < 2; ++ks) {                                            \
            const int jx = ((ks * 4 + q) ^ (ln & 7)) * 16;                          \
            intv4 a[8], b[4];                                                       \
            _Pragma("unroll")                                                       \
            for (int i = 0; i < 8; ++i) a[i] = *(const intv4*)(sa_ + baseA + i * 2048 + jx); \
            _Pragma("unroll")                                                       \
            for (int j = 0; j < 4; ++j) b[j] = *(const intv4*)(sb_ + baseB + j * 2048 + jx); \
            __builtin_amdgcn_s_setprio(1);                                          \
            _Pragma("unroll")                                                       \
            for (int i = 0; i < 8; ++i)                                             \
                _Pragma("unroll")                                                   \
                for (int j = 0; j < 4; ++j)                                         \
                    acc[i][j] = __builtin_amdgcn_mfma_i32_16x16x64_i8(a[i], b[j], acc[i][j], 0, 0, 0); \
            __builtin_amdgcn_s_setprio(0);                                          \
        }                                                                           \
    } while (0)

    STAGE_KT(0, 0);
#pragma unroll
    for (int kt = 0; kt < 8; ++kt) {
        if (kt < 7) {
            STAGE_KT(kt + 1, (kt + 1) & 1);   // issued after prev end-barrier: WAR-safe
            asm volatile("s_waitcnt vmcnt(8)" ::: "memory");   // kt's 8 loads done; kt+1's stay in flight
        } else {
            asm volatile("s_waitcnt vmcnt(0)" ::: "memory");
        }
        __builtin_amdgcn_s_barrier();          // all waves' kt staging visible
        COMPUTE_KT(kt & 1);
        asm volatile("" ::: "memory");
        __builtin_amdgcn_s_barrier();          // all waves done reading slot kt&1 -> may overwrite next iter
    }
#undef STAGE_KT
#undef COMPUTE_KT

    // epilogue: g = gb[n] - 2*s/QS^2; per-(row, 64-tile) f32 min + 4-bit residual (step 1.0)
    // resq layout: u16 slot = tile64*16 + (n&15), nibble = (n>>4)&3 = j. Each wave owns ONE 64-tile.
    float gbv[4];
#pragma unroll
    for (int j = 0; j < 4; ++j) gbv[j] = gbp[n0 + wn * 64 + j * 16 + ln];
    const float cf = 2.0f * INV_QS2;
    const int tile64 = nt * 4 + wn;
#pragma unroll
    for (int i = 0; i < 8; ++i) {
#pragma unroll
        for (int r = 0; r < 4; ++r) {
            const int m = m0 + wm * 128 + i * 16 + q * 4 + r;
            float g[4];
            float mn = 3.4e38f;
#pragma unroll
            for (int j = 0; j < 4; ++j) {
                g[j] = gbv[j] - cf * (float)acc[i][j][r];
                mn = fminf(mn, g[j]);
            }
#pragma unroll
            for (int o = 1; o < 16; o <<= 1) mn = fminf(mn, __shfl_xor(mn, o));
            if (ln == 0) tminp[(size_t)m * 64 + tile64] = mn;
            unsigned u = 0;
#pragma unroll
            for (int j = 0; j < 4; ++j) {
                int a4 = (int)rintf(g[j] - mn);
                a4 = (a4 > 15) ? 15 : a4;
                u |= (unsigned)a4 << (4 * j);
            }
            resq[(size_t)m * 1024 + tile64 * 16 + ln] = (unsigned short)u;
        }
    }
}

// ---------------- resolve winner per row: tile-pruned; exact f32 re-rank only on ties ----------------
__global__ __launch_bounds__(256) void resolve_k(const unsigned short* __restrict__ resq,
                                                 const float* __restrict__ tminp,
                                                 const float* __restrict__ x2p,
                                                 const float* __restrict__ x, const float* __restrict__ w,
                                                 const float* __restrict__ w2p, const float* __restrict__ rsump,
                                                 const float* __restrict__ ncp,
                                                 int* __restrict__ win) {
    const int lane = threadIdx.x & 63, wave = threadIdx.x >> 6;
    const int b = (blockIdx.x << 2) + wave;
    const float tv = tminp[(size_t)b * 64 + lane];   // lane = 64-col tile index
    float rowmin = tv;
#pragma unroll
    for (int o = 32; o; o >>= 1) rowmin = fminf(rowmin, __shfl_xor(rowmin, o));
    const float th = rowmin + MARGIN_G;
    const float thq = th + 0.5f;                     // +0.5 nibble-quant slack
    const unsigned long long tmask = __ballot(tv <= th);
    const float x2v = x2p[b];
    const unsigned short* rrow = resq + (size_t)b * 1024;
    const int nibsh = (lane >> 4) * 4;

    int cnt = 0, myn = -1;
    float myg = 0.0f;
    unsigned long long tm = tmask;
    while (tm) {
        const int tt = __ffsll((long long)tm) - 1;
        tm &= tm - 1;
        const float tb = __shfl(tv, tt);
        const unsigned short pv = rrow[tt * 16 + (lane & 15)];
        const float g = tb + (float)((pv >> nibsh) & 15);
        const bool c = (g <= thq);
        cnt += __popcll(__ballot(c));
        if (c && myn < 0) { myn = tt * 64 + lane; myg = g; }
    }

    if (cnt == 1) {
        if (myn >= 0) {
            const float act = ncp[myn] * (float)D_DIM / ((float)D_DIM + x2v + myg);
            win[b] = (act >= ATc) ? myn : -1;
        }
    } else {
        // exact f32 re-rank of all candidates
        const float4* xr = (const float4*)(x + (size_t)b * D_DIM);
        float4 xv[4];
#pragma unroll
        for (int j = 0; j < 4; ++j) xv[j] = xr[lane + j * 64];
        float best_act = -1.0f;
        int best_n = N_DIM;
        tm = tmask;
        while (tm) {
            const int tt = __ffsll((long long)tm) - 1;
            tm &= tm - 1;
            const float tb = __shfl(tv, tt);
            const unsigned short pv = rrow[tt * 16 + (lane & 15)];
            const float g = tb + (float)((pv >> nibsh) & 15);
            unsigned long long cm = __ballot(g <= thq);
            while (cm) {
                const int l = __ffsll((long long)cm) - 1;
                cm &= cm - 1;
                const int n = tt * 64 + l;
                const float4* wr = (const float4*)(w + (size_t)n * D_DIM);
                float p = 0.f;
#pragma unroll
                for (int j = 0; j < 4; ++j) {
                    const float4 wv = wr[lane + j * 64];
                    p += xv[j].x * wv.x + xv[j].y * wv.y + xv[j].z * wv.z + xv[j].w * wv.w;
                }
#pragma unroll
                for (int o = 32; o; o >>= 1) p += __shfl_xor(p, o);
                const float dist = x2v + w2p[n] - 2.0f * p;
                const float rs = rsump[n];
                const float dw = dist * rs * (1.0f / (float)D_DIM);
                const float a = rs * ncp[n] / (rs + dw + 1e-7f);
                if (a > best_act || (a == best_act && n < best_n)) { best_act = a; best_n = n; }
            }
        }
        if (lane == 0) win[b] = (best_act >= ATc) ? best_n : -1;
    }
}

// ---------------- per-node gather + update + outputs ----------------
__global__ __launch_bounds__(256) void finalize_k(const float* __restrict__ x, const float* __restrict__ w,
                                                  const float* __restrict__ mavg, const int* __restrict__ win,
                                                  float* __restrict__ out) {
    const int n = blockIdx.x, t = threadIdx.x;
    __shared__ unsigned short list[B_DIM];
    __shared__ int cnt;
    __shared__ float smax[4], smin[4], ssum[4];
    if (t == 0) cnt = 0;
    __syncthreads();
    const int4* wp = (const int4*)win;
#pragma unroll
    for (int k = 0; k < 8; ++k) {
        const int4 v = wp[k * 256 + t];
        const int b0 = (k * 256 + t) * 4;
        if (v.x == n) list[atomicAdd(&cnt, 1)] = (unsigned short)(b0 + 0);
        if (v.y == n) list[atomicAdd(&cnt, 1)] = (unsigned short)(b0 + 1);
        if (v.z == n) list[atomicAdd(&cnt, 1)] = (unsigned short)(b0 + 2);
        if (v.w == n) list[atomicAdd(&cnt, 1)] = (unsigned short)(b0 + 3);
    }
    __syncthreads();
    const int c = cnt;
    float4 s = {0.f, 0.f, 0.f, 0.f};
    for (int e = 0; e < c; ++e) {
        const float4 xv = ((const float4*)(x + (size_t)list[e] * D_DIM))[t];
        s.x += xv.x; s.y += xv.y; s.z += xv.z; s.w += xv.w;
    }
    const float has = (c > 0) ? 1.0f : 0.0f;
    const float invc = 1.0f / fmaxf((float)c, 1.0f);
    const size_t base4 = (size_t)n * (D_DIM / 4);
    const float4 wv = ((const float4*)w)[base4 + t];
    const float4 mk = ((const float4*)mavg)[base4 + t];
    float4 ms, mv;
    ms.x = s.x * invc; ms.y = s.y * invc; ms.z = s.z * invc; ms.w = s.w * invc;
    mv.x = EMAc * fabsf(ms.x - wv.x) + (1.0f - EMAc) * mk.x;
    mv.y = EMAc * fabsf(ms.y - wv.y) + (1.0f - EMAc) * mk.y;
    mv.z = EMAc * fabsf(ms.z - wv.z) + (1.0f - EMAc) * mk.z;
    mv.w = EMAc * fabsf(ms.w - wv.w) + (1.0f - EMAc) * mk.w;
    float lmax = fmaxf(fmaxf(mv.x, mv.y), fmaxf(mv.z, mv.w));
    float lmin = fminf(fminf(mv.x, mv.y), fminf(mv.z, mv.w));
    float lsum = mv.x + mv.y + mv.z + mv.w;
#pragma unroll
    for (int o = 32; o; o >>= 1) {
        lmax = fmaxf(lmax, __shfl_xor(lmax, o));
        lmin = fminf(lmin, __shfl_xor(lmin, o));
        lsum += __shfl_xor(lsum, o);
    }
    const int wave = t >> 6, lane = t & 63;
    if (lane == 0) { smax[wave] = lmax; smin[wave] = lmin; ssum[wave] = lsum; }
    __syncthreads();
    const float mx = fmaxf(fmaxf(smax[0], smax[1]), fmaxf(smax[2], smax[3]));
    const float mn = fminf(fminf(smin[0], smin[1]), fminf(smin[2], smin[3]));
    const float avg = (ssum[0] + ssum[1] + ssum[2] + ssum[3]) * (1.0f / (float)D_DIM);
    const float scale = 0.5f * (mx - mn);       // EPS_DS*(mx-mn)
    const float invs = (scale > 0.0f) ? 1.0f / scale : 0.0f;
    float4 relv;
    if (scale > 0.0f) {
        relv.x = 1.0f / (1.0f + __expf((mv.x - avg) * invs));
        relv.y = 1.0f / (1.0f + __expf((mv.y - avg) * invs));
        relv.z = 1.0f / (1.0f + __expf((mv.z - avg) * invs));
        relv.w = 1.0f / (1.0f + __expf((mv.w - avg) * invs));
    } else {
        relv.x = relv.y = relv.z = relv.w = 1.0f;
    }
    float4* o0 = (float4*)out;
    float4 r0, r1, r2;
    r0.x = ms.x * has; r0.y = ms.y * has; r0.z = ms.z * has; r0.w = ms.w * has;
    r1.x = (wv.x + LRc * (ms.x - wv.x)) * has;
    r1.y = (wv.y + LRc * (ms.y - wv.y)) * has;
    r1.z = (wv.z + LRc * (ms.z - wv.z)) * has;
    r1.w = (wv.w + LRc * (ms.w - wv.w)) * has;
    r2.x = relv.x * has; r2.y = relv.y * has; r2.z = relv.z * has; r2.w = relv.w * has;
    o0[base4 + t] = r0;
    o0[ND / 4 + base4 + t] = r1;
    o0[2 * (ND / 4) + base4 + t] = r2;
}

extern "C" void kernel_launch(void* const* d_in, const int* in_sizes, int n_in,
                              void* d_out, int out_size, void* d_ws, size_t ws_size,
                              hipStream_t stream) {
    const float* x    = (const float*)d_in[0];
    const float* w    = (const float*)d_in[1];
    const float* rel  = (const float*)d_in[2];
    const float* mavg = (const float*)d_in[3];
    const float* nc   = (const float*)d_in[4];
    float* out = (float*)d_out;

    char* p = (char*)d_ws;
    size_t off = 0;
    auto take = [&](size_t bytes) -> char* {
        char* r = p + off;
        off += (bytes + 255) & ~(size_t)255;
        return r;
    };
    signed char* xq = (signed char*)take((size_t)B_DIM * D_DIM);
    signed char* wq = (signed char*)take((size_t)N_DIM * D_DIM);
    float* x2       = (float*)take((size_t)B_DIM * 4);
    float* w2       = (float*)take((size_t)N_DIM * 4);
    float* rsum     = (float*)take((size_t)N_DIM * 4);
    float* gb       = (float*)take((size_t)N_DIM * 4);
    unsigned short* resq = (unsigned short*)take((size_t)B_DIM * 1024 * 2);  // 4-bit/node
    float* tminp    = (float*)take((size_t)B_DIM * 64 * 4);
    int* win        = (int*)take((size_t)B_DIM * 4);

    static bool attr_set = false;
    if (!attr_set) {
        (void)hipFuncSetAttribute(reinterpret_cast<const void*>(gemm_k),
                                  hipFuncAttributeMaxDynamicSharedMemorySize, 131072);
        attr_set = true;
    }

    prep_k<<<(B_DIM + N_DIM) / 4, 256, 0, stream>>>(x, w, rel, xq, wq, x2, w2, rsum, gb);
    gemm_k<<<512, 512, 131072, stream>>>(xq, wq, gb, resq, tminp);
    resolve_k<<<B_DIM / 4, 256, 0, stream>>>(resq, tminp, x2, x, w, w2, rsum, nc, win);
    finalize_k<<<N_DIM, 256, 0, stream>>>(x, w, mavg, win, out);
}